// Round 4
// baseline (160.020 us; speedup 1.0000x reference)
//
#include <hip/hip_runtime.h>
#include <hip/hip_cooperative_groups.h>

namespace cg = cooperative_groups;

// x [B=32, C=256, H=128, W=128] f32; conv_w [1,2,3,3] f32
#define BATCH 32
#define CH    256
#define HH    128
#define WW    128
#define HW    (HH * WW)        // 16384
#define HW4   (HW / 4)         // 4096
#define TROWS 8
#define LW    (WW + 2)         // 130, padded row

typedef float f32x4 __attribute__((ext_vector_type(4)));

// Fused: phase 1 channel mean+max reduce (streams x, 537 MB),
// grid-wide sync, phase 2 3x3 conv (2->1, pad 1) + SiLU.
// Block = 8 output rows of one image. 512 blocks x 256 threads (2/CU,
// co-resident -> cooperative sync valid).
__global__ __launch_bounds__(256) void fused_sam(
    const float* __restrict__ x, const float* __restrict__ cw,
    float* __restrict__ red, float* __restrict__ out) {
    __shared__ float lin[2][TROWS + 2][LW];   // 10.4 KB

    int blk = blockIdx.x;            // 32*16 = 512
    int b   = blk >> 4;
    int r0  = (blk & 15) * TROWS;
    int tid = threadIdx.x;
    int lr  = tid >> 5;              // row within tile, 0..7
    int c4  = tid & 31;              // float4 col, 0..31
    int p4  = r0 * 32 + tid;         // == (blk&15)*256 + tid, in [0,HW4)

    // zero the two pad columns (all 10 rows x 2 ch)
    if (tid < 2 * (TROWS + 2)) {
        int ch  = tid / (TROWS + 2);
        int row = tid - ch * (TROWS + 2);
        lin[ch][row][0]      = 0.f;
        lin[ch][row][LW - 1] = 0.f;
    }

    // ---- phase 1: channel reduction (the 537 MB stream) ----
    const f32x4* xp = reinterpret_cast<const f32x4*>(x)
                      + (size_t)b * (size_t)CH * HW4 + p4;
    f32x4 s = {0.f, 0.f, 0.f, 0.f};
    f32x4 m = {-INFINITY, -INFINITY, -INFINITY, -INFINITY};
    #pragma unroll 16
    for (int c = 0; c < CH; ++c) {
        f32x4 t = __builtin_nontemporal_load(xp + (size_t)c * HW4);
        s += t;
        m.x = fmaxf(m.x, t.x);
        m.y = fmaxf(m.y, t.y);
        m.z = fmaxf(m.z, t.z);
        m.w = fmaxf(m.w, t.w);
    }
    f32x4 avg = s * (1.0f / (float)CH);

    // global copy for neighbors' halo reads
    f32x4* rp = reinterpret_cast<f32x4*>(red) + (size_t)b * (2 * HW4) + p4;
    rp[0]   = avg;
    rp[HW4] = m;

    // own 8 rows straight into the LDS conv tile (rows 1..8)
    float* da = &lin[0][1 + lr][1 + 4 * c4];
    da[0] = avg.x; da[1] = avg.y; da[2] = avg.z; da[3] = avg.w;
    float* dm = &lin[1][1 + lr][1 + 4 * c4];
    dm[0] = m.x;  dm[1] = m.y;  dm[2] = m.z;  dm[3] = m.w;

    float wg[18];
    #pragma unroll
    for (int i = 0; i < 18; ++i) wg[i] = cw[i];   // uniform

    cg::this_grid().sync();   // device-scope fence: red visible cross-XCD

    // ---- phase 2: stage 2 halo rows, then conv + SiLU ----
    const f32x4* red4 = reinterpret_cast<const f32x4*>(red);
    if (tid < 128) {
        int which = tid >> 6;          // 0 = top halo, 1 = bottom halo
        int ch    = (tid >> 5) & 1;
        int cc    = tid & 31;
        int gr    = which ? (r0 + TROWS) : (r0 - 1);
        int lrow  = which ? (TROWS + 1) : 0;
        f32x4 v = {0.f, 0.f, 0.f, 0.f};
        if (gr >= 0 && gr < HH)
            v = red4[((size_t)b * 2 + ch) * HW4 + gr * 32 + cc];
        float* dst = &lin[ch][lrow][1 + 4 * cc];
        dst[0] = v.x; dst[1] = v.y; dst[2] = v.z; dst[3] = v.w;
    }
    __syncthreads();

    int w0 = 4 * c4;
    float acc[4] = {0.f, 0.f, 0.f, 0.f};
    #pragma unroll
    for (int ch = 0; ch < 2; ++ch) {
        #pragma unroll
        for (int dr = 0; dr < 3; ++dr) {
            const float* rowp = &lin[ch][lr + dr][w0];  // padded, safe
            float e[6];
            #pragma unroll
            for (int k = 0; k < 6; ++k) e[k] = rowp[k];
            const float* wp = &wg[ch * 9 + dr * 3];
            #pragma unroll
            for (int j = 0; j < 4; ++j)
                acc[j] += e[j] * wp[0] + e[j + 1] * wp[1] + e[j + 2] * wp[2];
        }
    }

    float4 o;
    o.x = acc[0] / (1.f + expf(-acc[0]));
    o.y = acc[1] / (1.f + expf(-acc[1]));
    o.z = acc[2] / (1.f + expf(-acc[2]));
    o.w = acc[3] / (1.f + expf(-acc[3]));
    reinterpret_cast<float4*>(out)[(size_t)b * HW4 + (r0 + lr) * 32 + c4] = o;
}

extern "C" void kernel_launch(void* const* d_in, const int* in_sizes, int n_in,
                              void* d_out, int out_size, void* d_ws, size_t ws_size,
                              hipStream_t stream) {
    const float* x  = (const float*)d_in[0];   // [32,256,128,128] f32
    const float* cw = (const float*)d_in[1];   // [1,2,3,3] f32
    float* out = (float*)d_out;                // [32,1,128,128] f32
    float* red = (float*)d_ws;                 // [32,2,128,128] f32 = 4 MiB

    void* args[] = {(void*)&x, (void*)&cw, (void*)&red, (void*)&out};
    hipLaunchCooperativeKernel((void*)fused_sam, dim3(BATCH * (HH / TROWS)),
                               dim3(256), args, 0, stream);
}

// Round 5
// 121.340 us; speedup vs baseline: 1.3188x; 1.3188x over previous
//
#include <hip/hip_runtime.h>

// x [B=32, C=256, H=128, W=128] f32; conv_w [1,2,3,3] f32
#define BATCH 32
#define CH    256
#define CHH   128              // half the channels per block
#define HH    128
#define WW    128
#define HW    (HH * WW)        // 16384
#define HW4   (HW / 4)         // 4096

typedef float f32x4 __attribute__((ext_vector_type(4)));

// Kernel 1: channel partial mean+max, channels split 2-way for occupancy
// (1024 blocks = 4 blocks/CU = 16 waves/CU).
// red2 layout [B][4][HW]: plane 0 = sum(ch 0..127), 1 = sum(ch 128..255),
//                         2 = max(ch 0..127), 3 = max(ch 128..255)
__global__ __launch_bounds__(256) void reduce_mean_max(
    const float* __restrict__ x, float* __restrict__ red2) {
    int blk  = blockIdx.x;           // [0, 1024)
    int b    = blk >> 5;             // image
    int half = (blk >> 4) & 1;       // channel half
    int tile = blk & 15;             // spatial tile
    int tid  = threadIdx.x;
    int p4   = tile * 256 + tid;     // [0, HW4)

    const f32x4* xp = reinterpret_cast<const f32x4*>(x)
                      + ((size_t)b * CH + (size_t)half * CHH) * HW4 + p4;

    f32x4 s = {0.f, 0.f, 0.f, 0.f};
    f32x4 m = {-INFINITY, -INFINITY, -INFINITY, -INFINITY};
    #pragma unroll 16
    for (int c = 0; c < CHH; ++c) {
        f32x4 t = __builtin_nontemporal_load(xp + (size_t)c * HW4);
        s += t;
        m.x = fmaxf(m.x, t.x);
        m.y = fmaxf(m.y, t.y);
        m.z = fmaxf(m.z, t.z);
        m.w = fmaxf(m.w, t.w);
    }

    f32x4* rp = reinterpret_cast<f32x4*>(red2) + (size_t)b * (4 * HW4) + p4;
    rp[(size_t)half * HW4]       = s;   // sum plane
    rp[(size_t)(2 + half) * HW4] = m;   // max plane
}

// Kernel 2: combine partials + 3x3 conv (2->1 ch, pad 1) + SiLU.
// Block = 8 output rows of one image; LDS tile [2][10][130].
#define TROWS 8
#define LW    (WW + 2)    // 130, padded row

__global__ __launch_bounds__(256) void conv3x3_silu(
    const float* __restrict__ red2, const float* __restrict__ cw,
    float* __restrict__ out) {
    __shared__ float lin[2][TROWS + 2][LW];   // 10.4 KB

    int blk = blockIdx.x;            // 32*16 = 512 blocks
    int b   = blk >> 4;
    int r0  = (blk & 15) * TROWS;
    int tid = threadIdx.x;

    // zero the two pad columns
    if (tid < 2 * (TROWS + 2)) {
        int ch  = tid / (TROWS + 2);
        int row = tid - ch * (TROWS + 2);
        lin[ch][row][0]      = 0.f;
        lin[ch][row][LW - 1] = 0.f;
    }

    // stage 2 ch x 10 rows x 32 float4: ch0 = (sum_lo+sum_hi)/256,
    // ch1 = max(max_lo, max_hi). 640 slots, 1280 L2-resident loads.
    const f32x4* red4 = reinterpret_cast<const f32x4*>(red2)
                        + (size_t)b * (4 * HW4);
    const float inv = 1.0f / (float)CH;
    for (int l = tid; l < 640; l += 256) {
        int ch  = l / 320;
        int rem = l - ch * 320;
        int row = rem >> 5;          // 0..9
        int c4  = rem & 31;          // 0..31
        int gr  = r0 - 1 + row;
        f32x4 v = {0.f, 0.f, 0.f, 0.f};
        if (gr >= 0 && gr < HH) {
            const f32x4* p = red4 + gr * 32 + c4;
            if (ch == 0) {
                v = (p[0] + p[HW4]) * inv;
            } else {
                f32x4 a = p[2 * HW4], bb = p[3 * HW4];
                v.x = fmaxf(a.x, bb.x);
                v.y = fmaxf(a.y, bb.y);
                v.z = fmaxf(a.z, bb.z);
                v.w = fmaxf(a.w, bb.w);
            }
        }
        float* dst = &lin[ch][row][1 + 4 * c4];
        dst[0] = v.x; dst[1] = v.y; dst[2] = v.z; dst[3] = v.w;
    }

    float wg[18];
    #pragma unroll
    for (int i = 0; i < 18; ++i) wg[i] = cw[i];   // uniform

    __syncthreads();

    int lr = tid >> 5;               // output row in tile, 0..7
    int w0 = (tid & 31) * 4;         // first output col

    float acc[4] = {0.f, 0.f, 0.f, 0.f};
    #pragma unroll
    for (int ch = 0; ch < 2; ++ch) {
        #pragma unroll
        for (int dr = 0; dr < 3; ++dr) {
            const float* rowp = &lin[ch][lr + dr][w0];
            float e[6];
            #pragma unroll
            for (int k = 0; k < 6; ++k) e[k] = rowp[k];
            const float* wp = &wg[ch * 9 + dr * 3];
            #pragma unroll
            for (int j = 0; j < 4; ++j)
                acc[j] += e[j] * wp[0] + e[j + 1] * wp[1] + e[j + 2] * wp[2];
        }
    }

    float4 o;
    o.x = acc[0] / (1.f + expf(-acc[0]));
    o.y = acc[1] / (1.f + expf(-acc[1]));
    o.z = acc[2] / (1.f + expf(-acc[2]));
    o.w = acc[3] / (1.f + expf(-acc[3]));
    reinterpret_cast<float4*>(out)[(size_t)b * HW4 + (r0 + lr) * 32 + (w0 >> 2)] = o;
}

extern "C" void kernel_launch(void* const* d_in, const int* in_sizes, int n_in,
                              void* d_out, int out_size, void* d_ws, size_t ws_size,
                              hipStream_t stream) {
    const float* x  = (const float*)d_in[0];   // [32,256,128,128] f32
    const float* cw = (const float*)d_in[1];   // [1,2,3,3] f32
    float* out  = (float*)d_out;               // [32,1,128,128] f32
    float* red2 = (float*)d_ws;                // [32,4,128,128] f32 = 8 MiB

    reduce_mean_max<<<BATCH * 2 * 16, 256, 0, stream>>>(x, red2);
    conv3x3_silu<<<BATCH * (HH / TROWS), 256, 0, stream>>>(red2, cw, out);
}

// Round 6
// 93.867 us; speedup vs baseline: 1.7047x; 1.2927x over previous
//
#include <hip/hip_runtime.h>

// x [B=32, C=256, H=128, W=128] f32; conv_w [1,2,3,3] f32
#define BATCH 32
#define CH    256
#define HH    128
#define WW    128
#define HW    (HH * WW)        // 16384
#define HW4   (HW / 4)         // 4096

typedef float f32x4 __attribute__((ext_vector_type(4)));

// Kernel 1: per-spatial-position channel mean+max.
// One thread handles 4 consecutive spatial positions via float4 (nontemporal).
// 512 blocks = 2 blocks/CU = 8 waves/CU — measured best (R5's 1024-block
// split regressed: more concurrent HBM streams -> worse DRAM locality).
// red layout: [B][2][H][W]  (ch0 = mean, ch1 = max)
__global__ __launch_bounds__(256) void reduce_mean_max(
    const float* __restrict__ x, float* __restrict__ red) {
    int idx = blockIdx.x * blockDim.x + threadIdx.x;   // [0, B*HW4)
    int b  = idx >> 12;      // / HW4
    int p4 = idx & (HW4 - 1);

    const f32x4* xp = reinterpret_cast<const f32x4*>(x)
                      + (size_t)b * (size_t)CH * HW4 + p4;

    f32x4 s = {0.f, 0.f, 0.f, 0.f};
    f32x4 m = {-INFINITY, -INFINITY, -INFINITY, -INFINITY};
    #pragma unroll 16
    for (int c = 0; c < CH; ++c) {
        f32x4 t = __builtin_nontemporal_load(xp + (size_t)c * HW4);
        s += t;
        m.x = fmaxf(m.x, t.x);
        m.y = fmaxf(m.y, t.y);
        m.z = fmaxf(m.z, t.z);
        m.w = fmaxf(m.w, t.w);
    }

    const float inv = 1.0f / (float)CH;
    f32x4 avg = s * inv;

    f32x4* rp = reinterpret_cast<f32x4*>(red) + (size_t)b * (2 * HW4) + p4;
    rp[0]   = avg;   // channel 0: mean
    rp[HW4] = m;     // channel 1: max
}

// Kernel 2: 3x3 conv (2->1 ch, pad 1, OIHW weights) + SiLU.
// Block = 8 output rows of one image; LDS tile [2][10][130] (zero-padded
// width), coalesced float4 staging, each thread computes 4 pixels.
#define TROWS 8
#define LW    (WW + 2)    // 130, padded row

__global__ __launch_bounds__(256) void conv3x3_silu(
    const float* __restrict__ red, const float* __restrict__ cw,
    float* __restrict__ out) {
    __shared__ float lin[2][TROWS + 2][LW];   // 2*10*130*4 = 10.4 KB

    int blk = blockIdx.x;            // 32*16 = 512 blocks
    int b   = blk >> 4;
    int r0  = (blk & 15) * TROWS;
    int tid = threadIdx.x;

    // zero the two pad columns (20 row-channel pairs)
    if (tid < 2 * (TROWS + 2)) {
        int ch  = tid / (TROWS + 2);
        int row = tid - ch * (TROWS + 2);
        lin[ch][row][0]      = 0.f;
        lin[ch][row][LW - 1] = 0.f;
    }

    // stage 2 ch x 10 rows x 128 cols = 640 float4 loads, coalesced
    const float4* red4 = reinterpret_cast<const float4*>(red);
    for (int l = tid; l < 640; l += 256) {
        int ch  = l / 320;
        int rem = l - ch * 320;
        int row = rem >> 5;          // 0..9
        int c4  = rem & 31;          // 0..31
        int gr  = r0 - 1 + row;
        float4 v = make_float4(0.f, 0.f, 0.f, 0.f);
        if (gr >= 0 && gr < HH)
            v = red4[((size_t)b * 2 + ch) * HW4 + gr * 32 + c4];
        float* dst = &lin[ch][row][1 + 4 * c4];
        dst[0] = v.x; dst[1] = v.y; dst[2] = v.z; dst[3] = v.w;
    }

    float wg[18];
    #pragma unroll
    for (int i = 0; i < 18; ++i) wg[i] = cw[i];   // uniform -> s_loads

    __syncthreads();

    int lr = tid >> 5;               // 0..7  (output row within tile)
    int w0 = (tid & 31) * 4;         // 0..124 (first output col)

    float acc[4] = {0.f, 0.f, 0.f, 0.f};
    #pragma unroll
    for (int ch = 0; ch < 2; ++ch) {
        #pragma unroll
        for (int dr = 0; dr < 3; ++dr) {
            const float* rowp = &lin[ch][lr + dr][w0];  // [w0-1..w0+4] padded
            float e[6];
            #pragma unroll
            for (int k = 0; k < 6; ++k) e[k] = rowp[k];
            const float* wp = &wg[ch * 9 + dr * 3];
            #pragma unroll
            for (int j = 0; j < 4; ++j)
                acc[j] += e[j] * wp[0] + e[j + 1] * wp[1] + e[j + 2] * wp[2];
        }
    }

    float4 o;
    o.x = acc[0] / (1.f + expf(-acc[0]));
    o.y = acc[1] / (1.f + expf(-acc[1]));
    o.z = acc[2] / (1.f + expf(-acc[2]));
    o.w = acc[3] / (1.f + expf(-acc[3]));
    reinterpret_cast<float4*>(out)[(size_t)b * HW4 + (r0 + lr) * 32 + (w0 >> 2)] = o;
}

extern "C" void kernel_launch(void* const* d_in, const int* in_sizes, int n_in,
                              void* d_out, int out_size, void* d_ws, size_t ws_size,
                              hipStream_t stream) {
    const float* x  = (const float*)d_in[0];   // [32,256,128,128] f32
    const float* cw = (const float*)d_in[1];   // [1,2,3,3] f32
    float* out = (float*)d_out;                // [32,1,128,128] f32
    float* red = (float*)d_ws;                 // [32,2,128,128] f32 = 4 MiB

    reduce_mean_max<<<(BATCH * HW4) / 256, 256, 0, stream>>>(x, red);
    conv3x3_silu<<<BATCH * (HH / TROWS), 256, 0, stream>>>(red, cw, out);
}